// Round 1
// baseline (369.331 us; speedup 1.0000x reference)
//
#include <hip/hip_runtime.h>
#include <hip/hip_bf16.h>

// ---------------- common ----------------
typedef __attribute__((ext_vector_type(8))) short bf16x8;
typedef __attribute__((ext_vector_type(4))) float f32x4;
typedef __attribute__((ext_vector_type(4))) unsigned short u16x4;

#define TILE 128
#define BK 32
#define M_DIM 8192
#define N_DIM 4096
#define K_DIM 4096

static __device__ inline unsigned short f32_to_bf16(float f) {
  unsigned int u = __float_as_uint(f);
  unsigned int r = u + 0x7FFFu + ((u >> 16) & 1u);  // RNE; inputs are finite
  return (unsigned short)(r >> 16);
}
static __device__ inline float bf16_to_f32(unsigned short h) {
  return __uint_as_float(((unsigned int)h) << 16);
}

static __device__ inline void gload_lds16(const void* g, void* l) {
  __builtin_amdgcn_global_load_lds(
      (const __attribute__((address_space(1))) unsigned int*)g,
      (__attribute__((address_space(3))) unsigned int*)l,
      16, 0, 0);
}

// ---------------- prep: x fp32 -> bf16, plus row sums ----------------
__global__ __launch_bounds__(256) void prep_x_kernel(
    const float* __restrict__ x, unsigned short* __restrict__ xb,
    float* __restrict__ sx) {
  const int row = blockIdx.x;
  const int tid = threadIdx.x;
  const float4* xr = (const float4*)(x + (long)row * K_DIM);
  u16x4* xo = (u16x4*)(xb + (long)row * K_DIM);
  float sum = 0.f;
#pragma unroll
  for (int i = 0; i < 4; ++i) {
    float4 v = xr[i * 256 + tid];
    float vv[4] = {v.x, v.y, v.z, v.w};
    u16x4 h;
#pragma unroll
    for (int j = 0; j < 4; ++j) {
      unsigned short b = f32_to_bf16(vv[j]);
      h[j] = b;
      sum += bf16_to_f32(b);  // sum of rounded values for consistency
    }
    xo[i * 256 + tid] = h;
  }
#pragma unroll
  for (int off = 32; off > 0; off >>= 1) sum += __shfl_down(sum, off, 64);
  __shared__ float red[4];
  const int lane = tid & 63, wv = tid >> 6;
  if (lane == 0) red[wv] = sum;
  __syncthreads();
  if (tid == 0) sx[row] = red[0] + red[1] + red[2] + red[3];
}

// ---------------- prep: qweight int32 -> bf16 (exact, values 0..255) ----------------
__global__ __launch_bounds__(256) void prep_q_kernel(
    const int* __restrict__ q, unsigned short* __restrict__ qb, long n4) {
  long idx = (long)blockIdx.x * blockDim.x + threadIdx.x;
  const long stride = (long)gridDim.x * blockDim.x;
  const int4* qi = (const int4*)q;
  u16x4* qo = (u16x4*)qb;
  for (long i = idx; i < n4; i += stride) {
    int4 v = qi[i];
    u16x4 h;
    h[0] = f32_to_bf16((float)v.x);
    h[1] = f32_to_bf16((float)v.y);
    h[2] = f32_to_bf16((float)v.z);
    h[3] = f32_to_bf16((float)v.w);
    qo[i] = h;
  }
}

// ---------------- GEMM: C[m][n] = sum_k A[m][k]*B[n][k], fused dequant epilogue ----------------
// m97 structure: 128x128 tile, BK=32, 4 waves (2x2), 4x4 16x16 frags per wave.
__global__ __launch_bounds__(256) void wq_gemm_kernel(
    const unsigned short* __restrict__ A,   // xb [M][K] bf16
    const unsigned short* __restrict__ B,   // qb [N][K] bf16
    const float* __restrict__ sx,           // [M]
    const float* __restrict__ scales,       // [N]
    const float* __restrict__ zps,          // [N]
    const float* __restrict__ bias,         // [N]
    float* __restrict__ C) {                // [M][N]
  __shared__ __align__(16) unsigned short sA[TILE * BK];  // 8 KB
  __shared__ __align__(16) unsigned short sB[TILE * BK];  // 8 KB

  const int tid = threadIdx.x;
  const int lane = tid & 63;
  const int wv = tid >> 6;
  const int wr = wv >> 1, wc = wv & 1;  // 2x2 waves, each 64x64 output
  const int brow = blockIdx.y * TILE;
  const int bcol = blockIdx.x * TILE;

  f32x4 acc[4][4] = {};

  // Staging: tile is 128 rows x 64 bytes (32 bf16). Linear byte o in [0,8192):
  // row = o>>6, col byte = o&63. Each thread stages 2 chunks of 16B per matrix.
  const int o0 = (0 * 256 + tid) * 16;
  const int o1 = (1 * 256 + tid) * 16;
  const int wvb = tid & ~63;
  const int l0 = (0 * 256 + wvb) * 16;  // wave-uniform LDS byte base (HW adds lane*16)
  const int l1 = (1 * 256 + wvb) * 16;

  const char* Ab = (const char*)A;
  const char* Bb = (const char*)B;
  const char* gA0 = Ab + ((long)(brow + (o0 >> 6)) * K_DIM) * 2 + (o0 & 63);
  const char* gA1 = Ab + ((long)(brow + (o1 >> 6)) * K_DIM) * 2 + (o1 & 63);
  const char* gB0 = Bb + ((long)(bcol + (o0 >> 6)) * K_DIM) * 2 + (o0 & 63);
  const char* gB1 = Bb + ((long)(bcol + (o1 >> 6)) * K_DIM) * 2 + (o1 & 63);
  char* lA0 = (char*)sA + l0;
  char* lA1 = (char*)sA + l1;
  char* lB0 = (char*)sB + l0;
  char* lB1 = (char*)sB + l1;

  // Fragment read base: lane l reads 8 contiguous k at row (frag*16 + (l&15)),
  // k-offset (l>>4)*8  -> ds_read_b128.
  const unsigned short* pA = sA + (wr * 64 + (lane & 15)) * BK + (lane >> 4) * 8;
  const unsigned short* pB = sB + (wc * 64 + (lane & 15)) * BK + (lane >> 4) * 8;

  for (int kk = 0; kk < K_DIM; kk += BK) {
    const long kb = (long)kk * 2;
    gload_lds16(gA0 + kb, lA0);
    gload_lds16(gA1 + kb, lA1);
    gload_lds16(gB0 + kb, lB0);
    gload_lds16(gB1 + kb, lB1);
    __syncthreads();  // drain vmcnt: staged data visible

    bf16x8 af[4], bfr[4];
#pragma unroll
    for (int m = 0; m < 4; ++m) af[m] = *(const bf16x8*)(pA + m * 16 * BK);
#pragma unroll
    for (int n = 0; n < 4; ++n) bfr[n] = *(const bf16x8*)(pB + n * 16 * BK);
#pragma unroll
    for (int m = 0; m < 4; ++m)
#pragma unroll
      for (int n = 0; n < 4; ++n)
        acc[m][n] = __builtin_amdgcn_mfma_f32_16x16x32_bf16(af[m], bfr[n], acc[m][n], 0, 0, 0);
    __syncthreads();  // all waves done reading LDS before next stage
  }

  // Epilogue: C/D layout col=lane&15, row=(lane>>4)*4+j (m89-verified).
  float sc[4], zp[4], bs[4];
  int coln[4];
#pragma unroll
  for (int n = 0; n < 4; ++n) {
    coln[n] = bcol + wc * 64 + n * 16 + (lane & 15);
    sc[n] = scales[coln[n]];
    zp[n] = zps[coln[n]];
    bs[n] = bias[coln[n]];
  }
#pragma unroll
  for (int m = 0; m < 4; ++m) {
    const int row0 = brow + wr * 64 + m * 16 + ((lane >> 4) << 2);
    float sxv[4];
#pragma unroll
    for (int j = 0; j < 4; ++j) sxv[j] = sx[row0 + j];
#pragma unroll
    for (int n = 0; n < 4; ++n) {
#pragma unroll
      for (int j = 0; j < 4; ++j) {
        C[(long)(row0 + j) * N_DIM + coln[n]] =
            sc[n] * (acc[m][n][j] - zp[n] * sxv[j]) + bs[n];
      }
    }
  }
}

// ---------------- launch ----------------
extern "C" void kernel_launch(void* const* d_in, const int* in_sizes, int n_in,
                              void* d_out, int out_size, void* d_ws, size_t ws_size,
                              hipStream_t stream) {
  const float* x = (const float*)d_in[0];
  const int* qw = (const int*)d_in[1];
  const float* scales = (const float*)d_in[2];
  const float* zps = (const float*)d_in[3];
  const float* bias = (const float*)d_in[4];
  float* out = (float*)d_out;

  char* ws = (char*)d_ws;
  unsigned short* xb = (unsigned short*)ws;                              // 64 MB
  unsigned short* qb = (unsigned short*)(ws + (size_t)64 * 1024 * 1024); // 32 MB
  float* sx = (float*)(ws + (size_t)96 * 1024 * 1024);                   // 32 KB

  hipLaunchKernelGGL(prep_x_kernel, dim3(M_DIM), dim3(256), 0, stream, x, xb, sx);
  hipLaunchKernelGGL(prep_q_kernel, dim3(2048), dim3(256), 0, stream, qw, qb,
                     (long)((long)N_DIM * K_DIM / 4));
  hipLaunchKernelGGL(wq_gemm_kernel, dim3(N_DIM / TILE, M_DIM / TILE), dim3(256), 0,
                     stream, xb, qb, sx, scales, zps, bias, out);
}

// Round 2
// 319.874 us; speedup vs baseline: 1.1546x; 1.1546x over previous
//
#include <hip/hip_runtime.h>
#include <hip/hip_bf16.h>

// ---------------- common ----------------
typedef __attribute__((ext_vector_type(8))) short bf16x8;
typedef __attribute__((ext_vector_type(4))) float f32x4;
typedef __attribute__((ext_vector_type(4))) unsigned short u16x4;

#define M_DIM 8192
#define N_DIM 4096
#define K_DIM 4096
#define BM 256
#define BN 256
#define BK 32
#define RING 4
#define NT (K_DIM / BK)  // 128

static __device__ inline unsigned short f32_to_bf16(float f) {
  unsigned int u = __float_as_uint(f);
  unsigned int r = u + 0x7FFFu + ((u >> 16) & 1u);  // RNE; inputs are finite
  return (unsigned short)(r >> 16);
}
static __device__ inline float bf16_to_f32(unsigned short h) {
  return __uint_as_float(((unsigned int)h) << 16);
}

static __device__ inline void gload_lds16(const void* g, void* l) {
  __builtin_amdgcn_global_load_lds(
      (const __attribute__((address_space(1))) unsigned int*)g,
      (__attribute__((address_space(3))) unsigned int*)l,
      16, 0, 0);
}

// ---------------- prep: x fp32 -> bf16, plus row sums ----------------
__global__ __launch_bounds__(256) void prep_x_kernel(
    const float* __restrict__ x, unsigned short* __restrict__ xb,
    float* __restrict__ sx) {
  const int row = blockIdx.x;
  const int tid = threadIdx.x;
  const float4* xr = (const float4*)(x + (long)row * K_DIM);
  u16x4* xo = (u16x4*)(xb + (long)row * K_DIM);
  float sum = 0.f;
#pragma unroll
  for (int i = 0; i < 4; ++i) {
    float4 v = xr[i * 256 + tid];
    float vv[4] = {v.x, v.y, v.z, v.w};
    u16x4 h;
#pragma unroll
    for (int j = 0; j < 4; ++j) {
      unsigned short b = f32_to_bf16(vv[j]);
      h[j] = b;
      sum += bf16_to_f32(b);  // sum of rounded values for consistency
    }
    xo[i * 256 + tid] = h;
  }
#pragma unroll
  for (int off = 32; off > 0; off >>= 1) sum += __shfl_down(sum, off, 64);
  __shared__ float red[4];
  const int lane = tid & 63, wv = tid >> 6;
  if (lane == 0) red[wv] = sum;
  __syncthreads();
  if (tid == 0) sx[row] = red[0] + red[1] + red[2] + red[3];
}

// ---------------- prep: qweight int32 -> bf16 (exact, values 0..255) ----------------
__global__ __launch_bounds__(256) void prep_q_kernel(
    const int* __restrict__ q, unsigned short* __restrict__ qb, long n4) {
  long idx = (long)blockIdx.x * blockDim.x + threadIdx.x;
  const long stride = (long)gridDim.x * blockDim.x;
  const int4* qi = (const int4*)q;
  u16x4* qo = (u16x4*)qb;
  for (long i = idx; i < n4; i += stride) {
    int4 v = qi[i];
    u16x4 h;
    h[0] = f32_to_bf16((float)v.x);
    h[1] = f32_to_bf16((float)v.y);
    h[2] = f32_to_bf16((float)v.z);
    h[3] = f32_to_bf16((float)v.w);
    qo[i] = h;
  }
}

// ---------------- GEMM: 256x256 tile, BK=32, 4-deep LDS ring, counted vmcnt ----------------
// 8 waves (2Mx4N); per wave: 128x64 output = 8x4 16x16 frags; 32 MFMA + 12 ds_read_b128 / K-tile.
// Loads for K-tiles t+1..t+3 stay in flight across barriers (vmcnt(12), never 0 in main loop).
__global__ __launch_bounds__(512, 2) void wq_gemm_kernel(
    const unsigned short* __restrict__ A,   // xb [M][K] bf16
    const unsigned short* __restrict__ B,   // qb [N][K] bf16
    const float* __restrict__ sx,           // [M]
    const float* __restrict__ scales,       // [N]
    const float* __restrict__ zps,          // [N]
    const float* __restrict__ bias,         // [N]
    float* __restrict__ C) {                // [M][N]
  // 4 ring slots x {A,B} x 256 rows x 32 k  = 4*2*16KB = 128 KiB
  __shared__ __align__(16) unsigned short lds[RING][2][BM * BK];

  const int tid = threadIdx.x;
  const int lane = tid & 63;
  const int wv = tid >> 6;
  const int wr = wv >> 2, wc = wv & 3;  // 2x4 waves; wave tile 128 rows x 64 cols
  const int brow = blockIdx.y * BM;
  const int bcol = blockIdx.x * BN;

  f32x4 acc[8][4] = {};

  // Staging: each {A,B} slot is 16 KB = 256 rows x 64 bytes. Linear byte o:
  // row = o>>6, colbyte = o&63. 512 threads x 16B = 8 KB per sweep, 2 sweeps per matrix.
  const int oa0 = tid * 16;         // sweep 0 byte offset
  const int oa1 = 8192 + tid * 16;  // sweep 1 byte offset
  const int wub = (tid & ~63) * 16; // wave-uniform LDS base (HW adds lane*16)

  const char* gA0 = (const char*)A + ((long)(brow + (oa0 >> 6)) * K_DIM) * 2 + (oa0 & 63);
  const char* gA1 = (const char*)A + ((long)(brow + (oa1 >> 6)) * K_DIM) * 2 + (oa1 & 63);
  const char* gB0 = (const char*)B + ((long)(bcol + (oa0 >> 6)) * K_DIM) * 2 + (oa0 & 63);
  const char* gB1 = (const char*)B + ((long)(bcol + (oa1 >> 6)) * K_DIM) * 2 + (oa1 & 63);

  auto stage = [&](int t) {
    const int s = t & (RING - 1);
    const long kb = (long)t * (BK * 2);
    char* la = (char*)&lds[s][0][0];
    char* lb = (char*)&lds[s][1][0];
    gload_lds16(gA0 + kb, la + wub);
    gload_lds16(gA1 + kb, la + 8192 + wub);
    gload_lds16(gB0 + kb, lb + wub);
    gload_lds16(gB1 + kb, lb + 8192 + wub);
  };

  auto compute = [&](int t) {
    const int s = t & (RING - 1);
    const unsigned short* pA = &lds[s][0][(wr * 128 + (lane & 15)) * BK + (lane >> 4) * 8];
    const unsigned short* pB = &lds[s][1][(wc * 64 + (lane & 15)) * BK + (lane >> 4) * 8];
    bf16x8 af[8], bfr[4];
#pragma unroll
    for (int m = 0; m < 8; ++m) af[m] = *(const bf16x8*)(pA + m * 16 * BK);
#pragma unroll
    for (int n = 0; n < 4; ++n) bfr[n] = *(const bf16x8*)(pB + n * 16 * BK);
    __builtin_amdgcn_s_setprio(1);
#pragma unroll
    for (int m = 0; m < 8; ++m)
#pragma unroll
      for (int n = 0; n < 4; ++n)
        acc[m][n] = __builtin_amdgcn_mfma_f32_16x16x32_bf16(af[m], bfr[n], acc[m][n], 0, 0, 0);
    __builtin_amdgcn_s_setprio(0);
  };

  // Prologue: 3 K-tiles in flight before first compute.
  stage(0);
  stage(1);
  stage(2);

  // Main loop: issue tile kt+3, allow tiles kt+1..kt+3 (12 loads) in flight,
  // force tile kt landed (vmcnt decrements in issue order).
  for (int kt = 0; kt < NT - 3; ++kt) {
    stage(kt + 3);
    asm volatile("s_waitcnt vmcnt(12)" ::: "memory");
    asm volatile("s_barrier" ::: "memory");
    compute(kt);
    asm volatile("s_barrier" ::: "memory");
  }
  // Tail: drain 8 -> 4 -> 0.
  asm volatile("s_waitcnt vmcnt(8)" ::: "memory");
  asm volatile("s_barrier" ::: "memory");
  compute(NT - 3);
  asm volatile("s_barrier" ::: "memory");
  asm volatile("s_waitcnt vmcnt(4)" ::: "memory");
  asm volatile("s_barrier" ::: "memory");
  compute(NT - 2);
  asm volatile("s_barrier" ::: "memory");
  asm volatile("s_waitcnt vmcnt(0)" ::: "memory");
  asm volatile("s_barrier" ::: "memory");
  compute(NT - 1);

  // Epilogue: C/D layout col=lane&15, row=(lane>>4)*4+j (m89-verified) + dequant fold.
  float sc[4], zp[4], bs[4];
  int coln[4];
#pragma unroll
  for (int n = 0; n < 4; ++n) {
    coln[n] = bcol + wc * 64 + n * 16 + (lane & 15);
    sc[n] = scales[coln[n]];
    zp[n] = zps[coln[n]];
    bs[n] = bias[coln[n]];
  }
#pragma unroll
  for (int m = 0; m < 8; ++m) {
    const int row0 = brow + wr * 128 + m * 16 + ((lane >> 4) << 2);
    float sxv[4];
#pragma unroll
    for (int j = 0; j < 4; ++j) sxv[j] = sx[row0 + j];
#pragma unroll
    for (int n = 0; n < 4; ++n) {
#pragma unroll
      for (int j = 0; j < 4; ++j) {
        C[(long)(row0 + j) * N_DIM + coln[n]] =
            sc[n] * (acc[m][n][j] - zp[n] * sxv[j]) + bs[n];
      }
    }
  }
}

// ---------------- launch ----------------
extern "C" void kernel_launch(void* const* d_in, const int* in_sizes, int n_in,
                              void* d_out, int out_size, void* d_ws, size_t ws_size,
                              hipStream_t stream) {
  const float* x = (const float*)d_in[0];
  const int* qw = (const int*)d_in[1];
  const float* scales = (const float*)d_in[2];
  const float* zps = (const float*)d_in[3];
  const float* bias = (const float*)d_in[4];
  float* out = (float*)d_out;

  char* ws = (char*)d_ws;
  unsigned short* xb = (unsigned short*)ws;                              // 64 MB
  unsigned short* qb = (unsigned short*)(ws + (size_t)64 * 1024 * 1024); // 32 MB
  float* sx = (float*)(ws + (size_t)96 * 1024 * 1024);                   // 32 KB

  hipLaunchKernelGGL(prep_x_kernel, dim3(M_DIM), dim3(256), 0, stream, x, xb, sx);
  hipLaunchKernelGGL(prep_q_kernel, dim3(2048), dim3(256), 0, stream, qw, qb,
                     (long)((long)N_DIM * K_DIM / 4));
  hipLaunchKernelGGL(wq_gemm_kernel, dim3(N_DIM / BN, M_DIM / BM), dim3(512), 0,
                     stream, xb, qb, sx, scales, zps, bias, out);
}

// Round 3
// 318.166 us; speedup vs baseline: 1.1608x; 1.0054x over previous
//
#include <hip/hip_runtime.h>
#include <hip/hip_bf16.h>

// ---------------- common ----------------
typedef __attribute__((ext_vector_type(8))) short bf16x8;
typedef __attribute__((ext_vector_type(4))) float f32x4;
typedef __attribute__((ext_vector_type(4))) unsigned short u16x4;

#define M_DIM 8192
#define N_DIM 4096
#define K_DIM 4096
#define BM 256
#define BN 256
#define BK 32
#define RING 4
#define NT (K_DIM / BK)  // 128

static __device__ inline unsigned short f32_to_bf16(float f) {
  unsigned int u = __float_as_uint(f);
  unsigned int r = u + 0x7FFFu + ((u >> 16) & 1u);  // RNE; inputs are finite
  return (unsigned short)(r >> 16);
}
static __device__ inline float bf16_to_f32(unsigned short h) {
  return __uint_as_float(((unsigned int)h) << 16);
}

static __device__ inline void gload_lds16(const void* g, void* l) {
  __builtin_amdgcn_global_load_lds(
      (const __attribute__((address_space(1))) unsigned int*)g,
      (__attribute__((address_space(3))) unsigned int*)l,
      16, 0, 0);
}

// ---------------- prep: x fp32 -> bf16, plus row sums ----------------
__global__ __launch_bounds__(256) void prep_x_kernel(
    const float* __restrict__ x, unsigned short* __restrict__ xb,
    float* __restrict__ sx) {
  const int row = blockIdx.x;
  const int tid = threadIdx.x;
  const float4* xr = (const float4*)(x + (long)row * K_DIM);
  u16x4* xo = (u16x4*)(xb + (long)row * K_DIM);
  float sum = 0.f;
#pragma unroll
  for (int i = 0; i < 4; ++i) {
    float4 v = xr[i * 256 + tid];
    float vv[4] = {v.x, v.y, v.z, v.w};
    u16x4 h;
#pragma unroll
    for (int j = 0; j < 4; ++j) {
      unsigned short b = f32_to_bf16(vv[j]);
      h[j] = b;
      sum += bf16_to_f32(b);  // sum of rounded values for consistency
    }
    xo[i * 256 + tid] = h;
  }
#pragma unroll
  for (int off = 32; off > 0; off >>= 1) sum += __shfl_down(sum, off, 64);
  __shared__ float red[4];
  const int lane = tid & 63, wv = tid >> 6;
  if (lane == 0) red[wv] = sum;
  __syncthreads();
  if (tid == 0) sx[row] = red[0] + red[1] + red[2] + red[3];
}

// ---------------- prep: qweight int32 -> bf16 (exact, values 0..255) ----------------
__global__ __launch_bounds__(256) void prep_q_kernel(
    const int* __restrict__ q, unsigned short* __restrict__ qb, long n4) {
  long idx = (long)blockIdx.x * blockDim.x + threadIdx.x;
  const long stride = (long)gridDim.x * blockDim.x;
  const int4* qi = (const int4*)q;
  u16x4* qo = (u16x4*)qb;
  for (long i = idx; i < n4; i += stride) {
    int4 v = qi[i];
    u16x4 h;
    h[0] = f32_to_bf16((float)v.x);
    h[1] = f32_to_bf16((float)v.y);
    h[2] = f32_to_bf16((float)v.z);
    h[3] = f32_to_bf16((float)v.w);
    qo[i] = h;
  }
}

// ---------------- GEMM: 256x256 tile, BK=32, 4-deep LDS ring, counted vmcnt ----------------
// T2 swizzle for 64B rows: 16B-chunk index ci' = ci ^ (row&3), applied BOTH on the
// global source address (LDS dest stays linear per global_load_lds) and on the
// ds_read address (rule #21: same involution on both sides).
// Read rows step by 16 (≡0 mod 4) so the XOR term is lane-constant -> folds into base ptr.
__global__ __launch_bounds__(512, 2) void wq_gemm_kernel(
    const unsigned short* __restrict__ A,   // xb [M][K] bf16
    const unsigned short* __restrict__ B,   // qb [N][K] bf16
    const float* __restrict__ sx,           // [M]
    const float* __restrict__ scales,       // [N]
    const float* __restrict__ zps,          // [N]
    const float* __restrict__ bias,         // [N]
    float* __restrict__ C) {                // [M][N]
  // 4 ring slots x {A,B} x 256 rows x 32 k  = 4*2*16KB = 128 KiB
  __shared__ __align__(16) unsigned short lds[RING][2][BM * BK];

  const int tid = threadIdx.x;
  const int lane = tid & 63;
  const int wv = tid >> 6;
  const int wr = wv >> 2, wc = wv & 3;  // 2x4 waves; wave tile 128 rows x 64 cols
  const int brow = blockIdx.y * BM;
  const int bcol = blockIdx.x * BN;

  f32x4 acc[8][4] = {};

  // Staging: each {A,B} slot is 16 KB = 256 rows x 64 bytes. Linear LDS byte o:
  // row = o>>6, chunk = (o>>4)&3. Source chunk = chunk ^ (row&3)  (pre-swizzled global).
  const int oa0 = tid * 16;         // sweep 0
  const int oa1 = 8192 + tid * 16;  // sweep 1
  const int wub = (tid & ~63) * 16; // wave-uniform LDS base (HW adds lane*16)

  const int r0 = oa0 >> 6, c0s = (((oa0 >> 4) & 3) ^ (r0 & 3)) * 16;
  const int r1 = oa1 >> 6, c1s = (((oa1 >> 4) & 3) ^ (r1 & 3)) * 16;

  const char* gA0 = (const char*)A + ((long)(brow + r0) * K_DIM) * 2 + c0s;
  const char* gA1 = (const char*)A + ((long)(brow + r1) * K_DIM) * 2 + c1s;
  const char* gB0 = (const char*)B + ((long)(bcol + r0) * K_DIM) * 2 + c0s;
  const char* gB1 = (const char*)B + ((long)(bcol + r1) * K_DIM) * 2 + c1s;

  auto stage = [&](int t) {
    const int s = t & (RING - 1);
    const long kb = (long)t * (BK * 2);
    char* la = (char*)&lds[s][0][0];
    char* lb = (char*)&lds[s][1][0];
    gload_lds16(gA0 + kb, la + wub);
    gload_lds16(gA1 + kb, la + 8192 + wub);
    gload_lds16(gB0 + kb, lb + wub);
    gload_lds16(gB1 + kb, lb + 8192 + wub);
  };

  // Read fragment base: row = (warp row) + (lane&15) [+ m*16], swizzled chunk =
  // (lane>>4) ^ (row&3); row&3 == lane&3 (other terms ≡ 0 mod 4).
  const int kchunk = ((lane >> 4) ^ (lane & 3)) * 8;  // elements

  auto compute = [&](int t) {
    const int s = t & (RING - 1);
    const unsigned short* pA = &lds[s][0][(wr * 128 + (lane & 15)) * BK + kchunk];
    const unsigned short* pB = &lds[s][1][(wc * 64 + (lane & 15)) * BK + kchunk];
    bf16x8 af[8], bfr[4];
#pragma unroll
    for (int m = 0; m < 8; ++m) af[m] = *(const bf16x8*)(pA + m * 16 * BK);
#pragma unroll
    for (int n = 0; n < 4; ++n) bfr[n] = *(const bf16x8*)(pB + n * 16 * BK);
    __builtin_amdgcn_s_setprio(1);
#pragma unroll
    for (int m = 0; m < 8; ++m)
#pragma unroll
      for (int n = 0; n < 4; ++n)
        acc[m][n] = __builtin_amdgcn_mfma_f32_16x16x32_bf16(af[m], bfr[n], acc[m][n], 0, 0, 0);
    __builtin_amdgcn_s_setprio(0);
  };

  // Prologue: 3 K-tiles in flight before first compute.
  stage(0);
  stage(1);
  stage(2);

  // Main loop: issue tile kt+3, allow tiles kt+1..kt+3 (12 loads) in flight,
  // force tile kt landed (vmcnt decrements in issue order).
  for (int kt = 0; kt < NT - 3; ++kt) {
    stage(kt + 3);
    asm volatile("s_waitcnt vmcnt(12)" ::: "memory");
    asm volatile("s_barrier" ::: "memory");
    compute(kt);
    asm volatile("s_barrier" ::: "memory");
  }
  // Tail: drain 8 -> 4 -> 0.
  asm volatile("s_waitcnt vmcnt(8)" ::: "memory");
  asm volatile("s_barrier" ::: "memory");
  compute(NT - 3);
  asm volatile("s_barrier" ::: "memory");
  asm volatile("s_waitcnt vmcnt(4)" ::: "memory");
  asm volatile("s_barrier" ::: "memory");
  compute(NT - 2);
  asm volatile("s_barrier" ::: "memory");
  asm volatile("s_waitcnt vmcnt(0)" ::: "memory");
  asm volatile("s_barrier" ::: "memory");
  compute(NT - 1);

  // Epilogue: C/D layout col=lane&15, row=(lane>>4)*4+j (m89-verified) + dequant fold.
  float sc[4], zp[4], bs[4];
  int coln[4];
#pragma unroll
  for (int n = 0; n < 4; ++n) {
    coln[n] = bcol + wc * 64 + n * 16 + (lane & 15);
    sc[n] = scales[coln[n]];
    zp[n] = zps[coln[n]];
    bs[n] = bias[coln[n]];
  }
#pragma unroll
  for (int m = 0; m < 8; ++m) {
    const int row0 = brow + wr * 128 + m * 16 + ((lane >> 4) << 2);
    float sxv[4];
#pragma unroll
    for (int j = 0; j < 4; ++j) sxv[j] = sx[row0 + j];
#pragma unroll
    for (int n = 0; n < 4; ++n) {
#pragma unroll
      for (int j = 0; j < 4; ++j) {
        C[(long)(row0 + j) * N_DIM + coln[n]] =
            sc[n] * (acc[m][n][j] - zp[n] * sxv[j]) + bs[n];
      }
    }
  }
}

// ---------------- launch ----------------
extern "C" void kernel_launch(void* const* d_in, const int* in_sizes, int n_in,
                              void* d_out, int out_size, void* d_ws, size_t ws_size,
                              hipStream_t stream) {
  const float* x = (const float*)d_in[0];
  const int* qw = (const int*)d_in[1];
  const float* scales = (const float*)d_in[2];
  const float* zps = (const float*)d_in[3];
  const float* bias = (const float*)d_in[4];
  float* out = (float*)d_out;

  char* ws = (char*)d_ws;
  unsigned short* xb = (unsigned short*)ws;                              // 64 MB
  unsigned short* qb = (unsigned short*)(ws + (size_t)64 * 1024 * 1024); // 32 MB
  float* sx = (float*)(ws + (size_t)96 * 1024 * 1024);                   // 32 KB

  hipLaunchKernelGGL(prep_x_kernel, dim3(M_DIM), dim3(256), 0, stream, x, xb, sx);
  hipLaunchKernelGGL(prep_q_kernel, dim3(2048), dim3(256), 0, stream, qw, qb,
                     (long)((long)N_DIM * K_DIM / 4));
  hipLaunchKernelGGL(wq_gemm_kernel, dim3(N_DIM / BN, M_DIM / BM), dim3(512), 0,
                     stream, xb, qb, sx, scales, zps, bias, out);
}

// Round 4
// 305.079 us; speedup vs baseline: 1.2106x; 1.0429x over previous
//
#include <hip/hip_runtime.h>
#include <hip/hip_bf16.h>

// ---------------- common ----------------
typedef __attribute__((ext_vector_type(8))) short bf16x8;
typedef __attribute__((ext_vector_type(4))) float f32x4;
typedef __attribute__((ext_vector_type(4))) unsigned short u16x4;

#define M_DIM 8192
#define N_DIM 4096
#define K_DIM 4096
#define BM 256
#define BN 256
#define BK 64
#define NT2 (K_DIM / BK)  // 64

static __device__ inline unsigned short f32_to_bf16(float f) {
  unsigned int u = __float_as_uint(f);
  unsigned int r = u + 0x7FFFu + ((u >> 16) & 1u);  // RNE; inputs are finite
  return (unsigned short)(r >> 16);
}
static __device__ inline float bf16_to_f32(unsigned short h) {
  return __uint_as_float(((unsigned int)h) << 16);
}

static __device__ inline void gload_lds16(const void* g, void* l) {
  __builtin_amdgcn_global_load_lds(
      (const __attribute__((address_space(1))) unsigned int*)g,
      (__attribute__((address_space(3))) unsigned int*)l,
      16, 0, 0);
}

// ---------------- prep: x fp32 -> bf16, plus row sums ----------------
__global__ __launch_bounds__(256) void prep_x_kernel(
    const float* __restrict__ x, unsigned short* __restrict__ xb,
    float* __restrict__ sx) {
  const int row = blockIdx.x;
  const int tid = threadIdx.x;
  const float4* xr = (const float4*)(x + (long)row * K_DIM);
  u16x4* xo = (u16x4*)(xb + (long)row * K_DIM);
  float sum = 0.f;
#pragma unroll
  for (int i = 0; i < 4; ++i) {
    float4 v = xr[i * 256 + tid];
    float vv[4] = {v.x, v.y, v.z, v.w};
    u16x4 h;
#pragma unroll
    for (int j = 0; j < 4; ++j) {
      unsigned short b = f32_to_bf16(vv[j]);
      h[j] = b;
      sum += bf16_to_f32(b);  // sum of rounded values for consistency
    }
    xo[i * 256 + tid] = h;
  }
#pragma unroll
  for (int off = 32; off > 0; off >>= 1) sum += __shfl_down(sum, off, 64);
  __shared__ float red[4];
  const int lane = tid & 63, wv = tid >> 6;
  if (lane == 0) red[wv] = sum;
  __syncthreads();
  if (tid == 0) sx[row] = red[0] + red[1] + red[2] + red[3];
}

// ---------------- prep: qweight int32 -> bf16 (exact, values 0..255) ----------------
__global__ __launch_bounds__(256) void prep_q_kernel(
    const int* __restrict__ q, unsigned short* __restrict__ qb, long n4) {
  long idx = (long)blockIdx.x * blockDim.x + threadIdx.x;
  const long stride = (long)gridDim.x * blockDim.x;
  const int4* qi = (const int4*)q;
  u16x4* qo = (u16x4*)qb;
  for (long i = idx; i < n4; i += stride) {
    int4 v = qi[i];
    u16x4 h;
    h[0] = f32_to_bf16((float)v.x);
    h[1] = f32_to_bf16((float)v.y);
    h[2] = f32_to_bf16((float)v.z);
    h[3] = f32_to_bf16((float)v.w);
    qo[i] = h;
  }
}

// ---------------- GEMM: m201-template port ----------------
// 256x256 tile, BK=64 (128B rows), 2 LDS buffers (128 KiB), 8 waves (2Mx4N),
// 4 phases per K-tile, 16 MFMA/phase in setprio, st_16x32 swizzle
// (chunk16 ^= ((row>>2)&1)<<1, applied on pre-swizzled global src + read addr,
// LDS dest linear per global_load_lds). Counted vmcnt ledger:
//   stage order per tile t (for t+1): P0:{A0,A2} P1:{B0,B2} P2:{B1,B3} P3:{A1,A3}
//   vmcnt(4) before P2 (forces prev tile's A1,A3 = this tile's A sweeps 1,3)
//   vmcnt(2) at tile boundary (forces all but newest A1,A3)
__global__ __launch_bounds__(512, 2) void wq_gemm_kernel(
    const unsigned short* __restrict__ A,   // xb [M][K] bf16
    const unsigned short* __restrict__ B,   // qb [N][K] bf16
    const float* __restrict__ sx,           // [M]
    const float* __restrict__ scales,       // [N]
    const float* __restrict__ zps,          // [N]
    const float* __restrict__ bias,         // [N]
    float* __restrict__ C) {                // [M][N]
  __shared__ __align__(16) char lds[2 * 65536];  // [buf][A:32KB | B:32KB]

  const int tid = threadIdx.x;
  const int lane = tid & 63;
  const int wv = tid >> 6;
  const int wr = wv >> 2, wc = wv & 3;  // 2x4 waves; wave tile 128 rows x 64 cols
  const int brow = blockIdx.y * BM;
  const int bcol = blockIdx.x * BN;

  f32x4 acc[8][4] = {};
  bf16x8 afr[8], bf0[4], bf1[4];

  // ---- staging addresses (512 threads; sweep = 8KB = 64 rows x 128B) ----
  const int srow = tid >> 3;                                   // 0..63
  const int schunk = ((tid & 7) ^ (((tid >> 5) & 1) << 1)) * 16;  // pre-swizzled src chunk
  const int wub = (tid & ~63) * 16;                            // wave-uniform LDS base in sweep
  const char* gAs = (const char*)A + ((long)(brow + srow) * K_DIM) * 2 + schunk;
  const char* gBs = (const char*)B + ((long)(bcol + srow) * K_DIM) * 2 + schunk;
  char* ldsA0p = lds;                 // buf0 A
  char* ldsB0p = lds + 32768;        // buf0 B
  char* ldsA1p = lds + 65536;        // buf1 A
  char* ldsB1p = lds + 65536 + 32768;

#define STAGE(GBASE, LBASE, J, T1)                                      \
  gload_lds16((GBASE) + (long)(J) * 524288 + (long)(T1) * 128,          \
              (LBASE) + (J) * 8192 + wub)

  // ---- fragment read bases (swizzled chunk folds into per-lane base) ----
  const int swz = ((lane >> 4) ^ (((lane >> 2) & 1) << 1)) * 16;
  const int aro = (wr * 128 + (lane & 15)) * 128 + swz;
  const int bro = (wc * 64 + (lane & 15)) * 128 + swz;
  const char* paA0c = lds + aro;
  const char* paA1c = lds + 65536 + aro;
  const char* paB0c = lds + 32768 + bro;
  const char* paB1c = lds + 65536 + 32768 + bro;

#define READ_A(PBASE, MH)                                                     \
  do {                                                                        \
    _Pragma("unroll") for (int mp = 0; mp < 4; ++mp)                          \
      _Pragma("unroll") for (int ks = 0; ks < 2; ++ks)                        \
        afr[mp * 2 + ks] =                                                    \
            *(const bf16x8*)((PBASE) + (MH) * 8192 + mp * 2048 + ks * 64);    \
  } while (0)

#define READ_B(PBASE, NH, DST)                                                \
  do {                                                                        \
    _Pragma("unroll") for (int np = 0; np < 2; ++np)                          \
      _Pragma("unroll") for (int ks = 0; ks < 2; ++ks)                        \
        DST[np * 2 + ks] =                                                    \
            *(const bf16x8*)((PBASE) + (NH) * 4096 + np * 2048 + ks * 64);    \
  } while (0)

#define MMA_Q(MH, NH, BFR)                                                    \
  do {                                                                        \
    __builtin_amdgcn_s_setprio(1);                                            \
    _Pragma("unroll") for (int mp = 0; mp < 4; ++mp)                          \
      _Pragma("unroll") for (int np = 0; np < 2; ++np)                        \
        _Pragma("unroll") for (int ks = 0; ks < 2; ++ks)                      \
          acc[(MH) * 4 + mp][(NH) * 2 + np] =                                 \
              __builtin_amdgcn_mfma_f32_16x16x32_bf16(                        \
                  afr[mp * 2 + ks], BFR[np * 2 + ks],                         \
                  acc[(MH) * 4 + mp][(NH) * 2 + np], 0, 0, 0);                \
    __builtin_amdgcn_s_setprio(0);                                            \
  } while (0)

#define BAR() asm volatile("s_barrier" ::: "memory")
#define VMC(N) asm volatile("s_waitcnt vmcnt(" #N ")" ::: "memory")

  // ---- prologue: full stage of tile 0 into buf0 ----
  STAGE(gAs, ldsA0p, 0, 0); STAGE(gAs, ldsA0p, 2, 0);
  STAGE(gBs, ldsB0p, 0, 0); STAGE(gBs, ldsB0p, 2, 0);
  STAGE(gBs, ldsB0p, 1, 0); STAGE(gBs, ldsB0p, 3, 0);
  STAGE(gAs, ldsA0p, 1, 0); STAGE(gAs, ldsA0p, 3, 0);
  VMC(0);
  BAR();

  // ---- main loop: tiles 0..NT2-2, staging t+1 into other buf ----
  for (int t = 0; t < NT2 - 1; ++t) {
    const int cb = t & 1;
    const char* pa = cb ? paA1c : paA0c;
    const char* pb = cb ? paB1c : paB0c;
    char* dA = cb ? ldsA0p : ldsA1p;
    char* dB = cb ? ldsB0p : ldsB1p;
    const int t1 = t + 1;
    // P0
    READ_A(pa, 0);
    READ_B(pb, 0, bf0);
    STAGE(gAs, dA, 0, t1); STAGE(gAs, dA, 2, t1);
    BAR();
    MMA_Q(0, 0, bf0);
    BAR();
    // P1
    READ_B(pb, 1, bf1);
    STAGE(gBs, dB, 0, t1); STAGE(gBs, dB, 2, t1);
    BAR();
    MMA_Q(0, 1, bf1);
    VMC(4);  // prev tile's {A1,A3} landed -> P2's A[mh=1] reads safe
    BAR();
    // P2
    READ_A(pa, 1);
    STAGE(gBs, dB, 1, t1); STAGE(gBs, dB, 3, t1);
    BAR();
    MMA_Q(1, 0, bf0);
    BAR();
    // P3
    STAGE(gAs, dA, 1, t1); STAGE(gAs, dA, 3, t1);
    BAR();
    MMA_Q(1, 1, bf1);
    VMC(2);  // all of tile t+1 except its {A1,A3} landed -> next P0 safe
    BAR();
  }

  // ---- tail: tile NT2-1 (odd -> buf1), no staging ----
  {
    const char* pa = paA1c;
    const char* pb = paB1c;
    READ_A(pa, 0);
    READ_B(pb, 0, bf0);
    BAR();
    MMA_Q(0, 0, bf0);
    BAR();
    READ_B(pb, 1, bf1);
    BAR();
    MMA_Q(0, 1, bf1);
    VMC(0);  // drain remaining {A1,A3}
    BAR();
    READ_A(pa, 1);
    BAR();
    MMA_Q(1, 0, bf0);
    BAR();
    MMA_Q(1, 1, bf1);
  }

  // ---- epilogue: C/D layout col=lane&15, row=(lane>>4)*4+j + dequant fold ----
  float sc[4], zp[4], bs[4];
  int coln[4];
#pragma unroll
  for (int n = 0; n < 4; ++n) {
    coln[n] = bcol + wc * 64 + n * 16 + (lane & 15);
    sc[n] = scales[coln[n]];
    zp[n] = zps[coln[n]];
    bs[n] = bias[coln[n]];
  }
#pragma unroll
  for (int m = 0; m < 8; ++m) {
    const int row0 = brow + wr * 128 + m * 16 + ((lane >> 4) << 2);
    float sxv[4];
#pragma unroll
    for (int j = 0; j < 4; ++j) sxv[j] = sx[row0 + j];
#pragma unroll
    for (int n = 0; n < 4; ++n) {
#pragma unroll
      for (int j = 0; j < 4; ++j) {
        C[(long)(row0 + j) * N_DIM + coln[n]] =
            sc[n] * (acc[m][n][j] - zp[n] * sxv[j]) + bs[n];
      }
    }
  }
}

// ---------------- launch ----------------
extern "C" void kernel_launch(void* const* d_in, const int* in_sizes, int n_in,
                              void* d_out, int out_size, void* d_ws, size_t ws_size,
                              hipStream_t stream) {
  const float* x = (const float*)d_in[0];
  const int* qw = (const int*)d_in[1];
  const float* scales = (const float*)d_in[2];
  const float* zps = (const float*)d_in[3];
  const float* bias = (const float*)d_in[4];
  float* out = (float*)d_out;

  char* ws = (char*)d_ws;
  unsigned short* xb = (unsigned short*)ws;                              // 64 MB
  unsigned short* qb = (unsigned short*)(ws + (size_t)64 * 1024 * 1024); // 32 MB
  float* sx = (float*)(ws + (size_t)96 * 1024 * 1024);                   // 32 KB

  hipLaunchKernelGGL(prep_x_kernel, dim3(M_DIM), dim3(256), 0, stream, x, xb, sx);
  hipLaunchKernelGGL(prep_q_kernel, dim3(2048), dim3(256), 0, stream, qw, qb,
                     (long)((long)N_DIM * K_DIM / 4));
  hipLaunchKernelGGL(wq_gemm_kernel, dim3(N_DIM / BN, M_DIM / BM), dim3(512), 0,
                     stream, xb, qb, sx, scales, zps, bias, out);
}